// Round 1
// baseline (105.445 us; speedup 1.0000x reference)
//
#include <hip/hip_runtime.h>
#include <math.h>

#define NB 4
#define NT 256
#define NS 1024
#define NH 256
#define TT 8          // t rows per main block
#define SBK 256       // s per main block
#define NSQ (NS / SBK)

static constexpr float CTWO   = 2.8853900817779268f; // 2*log2(e)
static constexpr float LOG2E  = 1.4426950408889634f;
static constexpr float ACLAMP = 62.0f;

// ---------- projection: out[r][n] = exp2(clamp(CTWO * sum_k A[r][k]*W[k][n])) ----------
__global__ __launch_bounds__(256) void proj_kernel(const float* __restrict__ A,
                                                   const float* __restrict__ W,
                                                   float* __restrict__ out) {
  __shared__ float As[32][68];   // [k][m], padded
  __shared__ float Bs[32][68];   // [k][n], padded
  const int tid = threadIdx.x;
  const int r0 = blockIdx.x * 64;
  const int n0 = blockIdx.y * 64;
  const int tx = tid & 15;
  const int ty = tid >> 4;
  float acc[4][4] = {};
  for (int k0 = 0; k0 < NH; k0 += 32) {
    {
      const int r = tid >> 2;
      const int kq = (tid & 3) * 8;
      const float* src = A + (size_t)(r0 + r) * NH + k0 + kq;
      float4 v0 = *(const float4*)(src);
      float4 v1 = *(const float4*)(src + 4);
      As[kq + 0][r] = v0.x; As[kq + 1][r] = v0.y; As[kq + 2][r] = v0.z; As[kq + 3][r] = v0.w;
      As[kq + 4][r] = v1.x; As[kq + 5][r] = v1.y; As[kq + 6][r] = v1.z; As[kq + 7][r] = v1.w;
    }
    {
      const int k = tid >> 3;
      const int nq = (tid & 7) * 8;
      const float* src = W + (size_t)(k0 + k) * NH + n0 + nq;
      *(float4*)&Bs[k][nq]     = *(const float4*)(src);
      *(float4*)&Bs[k][nq + 4] = *(const float4*)(src + 4);
    }
    __syncthreads();
    #pragma unroll
    for (int k = 0; k < 32; ++k) {
      float4 a = *(const float4*)&As[k][ty * 4];
      float4 b = *(const float4*)&Bs[k][tx * 4];
      const float av[4] = {a.x, a.y, a.z, a.w};
      const float bv[4] = {b.x, b.y, b.z, b.w};
      #pragma unroll
      for (int i = 0; i < 4; ++i)
        #pragma unroll
        for (int j = 0; j < 4; ++j)
          acc[i][j] = fmaf(av[i], bv[j], acc[i][j]);
    }
    __syncthreads();
  }
  #pragma unroll
  for (int i = 0; i < 4; ++i) {
    #pragma unroll
    for (int j = 0; j < 4; ++j) {
      float x = acc[i][j] * CTWO;
      x = fminf(fmaxf(x, -ACLAMP), ACLAMP);
      out[(size_t)(r0 + ty * 4 + i) * NH + n0 + tx * 4 + j] = __builtin_amdgcn_exp2f(x);
    }
  }
}

// ---------- block-wide allreduce helpers (256 threads = 4 waves) ----------
__device__ __forceinline__ float allreduce_max(float x, float* red, int tid) {
  #pragma unroll
  for (int o = 32; o > 0; o >>= 1) x = fmaxf(x, __shfl_xor(x, o, 64));
  __syncthreads();
  if ((tid & 63) == 0) red[tid >> 6] = x;
  __syncthreads();
  return fmaxf(fmaxf(red[0], red[1]), fmaxf(red[2], red[3]));
}

__device__ __forceinline__ float allreduce_sum(float x, float* red, int tid) {
  #pragma unroll
  for (int o = 32; o > 0; o >>= 1) x += __shfl_xor(x, o, 64);
  __syncthreads();
  if ((tid & 63) == 0) red[tid >> 6] = x;
  __syncthreads();
  return (red[0] + red[1]) + (red[2] + red[3]);
}

// ---------- main: scores + partial softmax + partial PV per (b, t-tile, s-slab) ----------
__global__ __launch_bounds__(256) void attn_main_kernel(
    const float* __restrict__ tq, const float* __restrict__ te,
    const float* __restrict__ enc, const int* __restrict__ src_len,
    const float* __restrict__ v,
    float* __restrict__ po, float* __restrict__ mbuf, float* __restrict__ lbuf) {
  __shared__ float p_lds[TT][SBK];
  __shared__ float red[4];
  __shared__ float ml[2][TT];
  const int tid = threadIdx.x;
  const int sq = blockIdx.x;
  const int tt = blockIdx.y;
  const int b  = blockIdx.z;
  const int s0 = sq * SBK;
  const int len = src_len[b];
  const int btbase = b * NT + tt * TT;

  if (s0 >= len) {  // whole slab masked out
    #pragma unroll
    for (int t = 0; t < TT; ++t)
      po[((size_t)(btbase + t) * NSQ + sq) * NH + tid] = 0.f;
    if (tid < TT) {
      mbuf[(size_t)(btbase + tid) * NSQ + sq] = -INFINITY;
      lbuf[(size_t)(btbase + tid) * NSQ + sq] = 0.f;
    }
    return;
  }

  const float sumv = allreduce_sum(v[tid], red, tid);

  const int s = s0 + tid;
  const bool valid = s < len;
  const float* teRow = te + ((size_t)b * NS + s) * NH;
  const float* tqB = tq + (size_t)btbase * NH;

  float acc2[TT];
  #pragma unroll
  for (int t = 0; t < TT; ++t) acc2[t] = 0.f;

  for (int hc = 0; hc < NH / 32; ++hc) {
    float4 te4[8], v4[8];
    #pragma unroll
    for (int q = 0; q < 8; ++q) {
      te4[q] = *(const float4*)(teRow + hc * 32 + q * 4);
      v4[q]  = *(const float4*)(v + hc * 32 + q * 4);
    }
    #pragma unroll
    for (int t = 0; t < TT; ++t) {
      const float* tqr = tqB + (size_t)t * NH + hc * 32;
      float a = acc2[t];
      #pragma unroll
      for (int q = 0; q < 8; ++q) {
        float4 q4 = *(const float4*)(tqr + q * 4);
        a = fmaf(v4[q].x, __builtin_amdgcn_rcpf(fmaf(q4.x, te4[q].x, 1.0f)), a);
        a = fmaf(v4[q].y, __builtin_amdgcn_rcpf(fmaf(q4.y, te4[q].y, 1.0f)), a);
        a = fmaf(v4[q].z, __builtin_amdgcn_rcpf(fmaf(q4.z, te4[q].z, 1.0f)), a);
        a = fmaf(v4[q].w, __builtin_amdgcn_rcpf(fmaf(q4.w, te4[q].w, 1.0f)), a);
      }
      acc2[t] = a;
    }
  }

  // per-t softmax partials over this slab's 256 s
  #pragma unroll
  for (int t = 0; t < TT; ++t) {
    float score = valid ? fmaf(-2.f, acc2[t], sumv) : -INFINITY;
    float m = allreduce_max(score, red, tid);
    float p = __builtin_amdgcn_exp2f((score - m) * LOG2E);  // -inf -> 0
    float l = allreduce_sum(p, red, tid);
    p_lds[t][tid] = p;
    if (tid == 0) { ml[0][t] = m; ml[1][t] = l; }
  }
  __syncthreads();

  // partial PV: thread owns column h = tid
  float outv[TT];
  #pragma unroll
  for (int t = 0; t < TT; ++t) outv[t] = 0.f;
  const float* encB = enc + ((size_t)b * NS + s0) * NH + tid;
  for (int sl = 0; sl < SBK; sl += 4) {
    float4 pv[TT];
    #pragma unroll
    for (int t = 0; t < TT; ++t) pv[t] = *(const float4*)&p_lds[t][sl];
    float e0 = encB[(size_t)(sl + 0) * NH];
    float e1 = encB[(size_t)(sl + 1) * NH];
    float e2 = encB[(size_t)(sl + 2) * NH];
    float e3 = encB[(size_t)(sl + 3) * NH];
    #pragma unroll
    for (int t = 0; t < TT; ++t) {
      outv[t] = fmaf(pv[t].x, e0, outv[t]);
      outv[t] = fmaf(pv[t].y, e1, outv[t]);
      outv[t] = fmaf(pv[t].z, e2, outv[t]);
      outv[t] = fmaf(pv[t].w, e3, outv[t]);
    }
  }
  #pragma unroll
  for (int t = 0; t < TT; ++t)
    po[((size_t)(btbase + t) * NSQ + sq) * NH + tid] = outv[t];
  if (tid < TT) {
    mbuf[(size_t)(btbase + tid) * NSQ + sq] = ml[0][tid];
    lbuf[(size_t)(btbase + tid) * NSQ + sq] = ml[1][tid];
  }
}

// ---------- combine the NSQ slab-partials per (b,t) ----------
__global__ __launch_bounds__(256) void combine_kernel(const float* __restrict__ po,
                                                      const float* __restrict__ mbuf,
                                                      const float* __restrict__ lbuf,
                                                      float* __restrict__ out) {
  const int bt = blockIdx.x;
  const int h = threadIdx.x;
  float m[NSQ], l[NSQ];
  float M = -INFINITY;
  #pragma unroll
  for (int i = 0; i < NSQ; ++i) {
    m[i] = mbuf[(size_t)bt * NSQ + i];
    l[i] = lbuf[(size_t)bt * NSQ + i];
    M = fmaxf(M, m[i]);
  }
  float L = 0.f, o = 0.f;
  #pragma unroll
  for (int i = 0; i < NSQ; ++i) {
    float w = __builtin_amdgcn_exp2f((m[i] - M) * LOG2E);  // m=-inf -> w=0
    L = fmaf(w, l[i], L);
    o = fmaf(w, po[((size_t)bt * NSQ + i) * NH + h], o);
  }
  out[(size_t)bt * NH + h] = o / L;
}

extern "C" void kernel_launch(void* const* d_in, const int* in_sizes, int n_in,
                              void* d_out, int out_size, void* d_ws, size_t ws_size,
                              hipStream_t stream) {
  const float* query = (const float*)d_in[0];
  const float* enc   = (const float*)d_in[1];
  const int*   slen  = (const int*)d_in[2];
  const float* W_h   = (const float*)d_in[3];
  const float* W_s   = (const float*)d_in[4];
  const float* v     = (const float*)d_in[5];
  float* out = (float*)d_out;

  float* ws = (float*)d_ws;
  float* tq = ws;                                  // B*T*H
  float* te = tq + (size_t)NB * NT * NH;           // B*S*H
  float* po = te + (size_t)NB * NS * NH;           // B*T*NSQ*H
  float* mb = po + (size_t)NB * NT * NSQ * NH;     // B*T*NSQ
  float* lb = mb + (size_t)NB * NT * NSQ;          // B*T*NSQ

  hipLaunchKernelGGL(proj_kernel, dim3((NB * NT) / 64, NH / 64), dim3(256), 0, stream,
                     query, W_h, tq);
  hipLaunchKernelGGL(proj_kernel, dim3((NB * NS) / 64, NH / 64), dim3(256), 0, stream,
                     enc, W_s, te);
  hipLaunchKernelGGL(attn_main_kernel, dim3(NSQ, NT / TT, NB), dim3(256), 0, stream,
                     tq, te, enc, slen, v, po, mb, lb);
  hipLaunchKernelGGL(combine_kernel, dim3(NB * NT), dim3(256), 0, stream, po, mb, lb, out);
}

// Round 2
// 102.120 us; speedup vs baseline: 1.0326x; 1.0326x over previous
//
#include <hip/hip_runtime.h>
#include <math.h>

#define NB 4
#define NT 256
#define NS 1024
#define NH 256
#define TT 2          // t rows per main block
#define SBK 256       // s per main block
#define NSQ (NS / SBK)

static constexpr float CTWO   = 2.8853900817779268f; // 2*log2(e)
static constexpr float LOG2E  = 1.4426950408889634f;
static constexpr float ACLAMP = 62.0f;

// ---------- merged projection: rows [0,NB*NT) = query x W_h -> tq,
//            rows [NB*NT, NB*NT+NB*NS) = enc x W_s -> te.
// out[r][n] = exp2(clamp(CTWO * sum_k A[r][k]*W[k][n]))
__global__ __launch_bounds__(256) void proj_kernel(const float* __restrict__ Q,
                                                   const float* __restrict__ E,
                                                   const float* __restrict__ W_h,
                                                   const float* __restrict__ W_s,
                                                   float* __restrict__ tq,
                                                   float* __restrict__ te) {
  __shared__ float As[32][68];   // [k][m], padded
  __shared__ float Bs[32][68];   // [k][n], padded
  const int tid = threadIdx.x;
  int r0 = blockIdx.x * 64;
  const int n0 = blockIdx.y * 64;
  const float* A;
  const float* W;
  float* out;
  if (r0 < NB * NT) { A = Q; W = W_h; out = tq; }
  else              { A = E; W = W_s; out = te; r0 -= NB * NT; }
  const int tx = tid & 15;
  const int ty = tid >> 4;
  float acc[4][4] = {};
  for (int k0 = 0; k0 < NH; k0 += 32) {
    {
      const int r = tid >> 2;
      const int kq = (tid & 3) * 8;
      const float* src = A + (size_t)(r0 + r) * NH + k0 + kq;
      float4 v0 = *(const float4*)(src);
      float4 v1 = *(const float4*)(src + 4);
      As[kq + 0][r] = v0.x; As[kq + 1][r] = v0.y; As[kq + 2][r] = v0.z; As[kq + 3][r] = v0.w;
      As[kq + 4][r] = v1.x; As[kq + 5][r] = v1.y; As[kq + 6][r] = v1.z; As[kq + 7][r] = v1.w;
    }
    {
      const int k = tid >> 3;
      const int nq = (tid & 7) * 8;
      const float* src = W + (size_t)(k0 + k) * NH + n0 + nq;
      *(float4*)&Bs[k][nq]     = *(const float4*)(src);
      *(float4*)&Bs[k][nq + 4] = *(const float4*)(src + 4);
    }
    __syncthreads();
    #pragma unroll
    for (int k = 0; k < 32; ++k) {
      float4 a = *(const float4*)&As[k][ty * 4];
      float4 b = *(const float4*)&Bs[k][tx * 4];
      const float av[4] = {a.x, a.y, a.z, a.w};
      const float bv[4] = {b.x, b.y, b.z, b.w};
      #pragma unroll
      for (int i = 0; i < 4; ++i)
        #pragma unroll
        for (int j = 0; j < 4; ++j)
          acc[i][j] = fmaf(av[i], bv[j], acc[i][j]);
    }
    __syncthreads();
  }
  #pragma unroll
  for (int i = 0; i < 4; ++i) {
    #pragma unroll
    for (int j = 0; j < 4; ++j) {
      float x = acc[i][j] * CTWO;
      x = fminf(fmaxf(x, -ACLAMP), ACLAMP);
      out[(size_t)(r0 + ty * 4 + i) * NH + n0 + tx * 4 + j] = __builtin_amdgcn_exp2f(x);
    }
  }
}

// ---------- block-wide allreduce helpers (256 threads = 4 waves) ----------
__device__ __forceinline__ float allreduce_max(float x, float* red, int tid) {
  #pragma unroll
  for (int o = 32; o > 0; o >>= 1) x = fmaxf(x, __shfl_xor(x, o, 64));
  __syncthreads();
  if ((tid & 63) == 0) red[tid >> 6] = x;
  __syncthreads();
  return fmaxf(fmaxf(red[0], red[1]), fmaxf(red[2], red[3]));
}

__device__ __forceinline__ float allreduce_sum(float x, float* red, int tid) {
  #pragma unroll
  for (int o = 32; o > 0; o >>= 1) x += __shfl_xor(x, o, 64);
  __syncthreads();
  if ((tid & 63) == 0) red[tid >> 6] = x;
  __syncthreads();
  return (red[0] + red[1]) + (red[2] + red[3]);
}

// paired-rcp accumulate: contribution v1/ta + v2/tb = (v1*tb + v2*ta) / (ta*tb)
// 6 VALU + 1 trans per 2 elements.
#define PAIR(qa, ea, va, qb, eb, vb, ACC)                                  \
  {                                                                        \
    float ta = fmaf((qa), (ea), 1.0f);                                     \
    float tb = fmaf((qb), (eb), 1.0f);                                     \
    float num = fmaf((va), tb, (vb) * ta);                                 \
    float den = ta * tb;                                                   \
    ACC = fmaf(num, __builtin_amdgcn_rcpf(den), ACC);                      \
  }

// ---------- main: scores + partial softmax + partial PV per (b, t-tile, s-slab) ----------
__global__ __launch_bounds__(256) void attn_main_kernel(
    const float* __restrict__ tq, const float* __restrict__ te,
    const float* __restrict__ enc, const int* __restrict__ src_len,
    const float* __restrict__ v,
    float* __restrict__ po, float* __restrict__ mbuf, float* __restrict__ lbuf) {
  __shared__ float p_lds[TT][SBK];
  __shared__ float red[4];
  __shared__ float ml[2][TT];
  const int tid = threadIdx.x;
  const int sq = blockIdx.x;
  const int tt = blockIdx.y;
  const int b  = blockIdx.z;
  const int s0 = sq * SBK;
  const int len = src_len[b];
  const int btbase = b * NT + tt * TT;

  if (s0 >= len) {  // whole slab masked out
    #pragma unroll
    for (int t = 0; t < TT; ++t)
      po[((size_t)(btbase + t) * NSQ + sq) * NH + tid] = 0.f;
    if (tid < TT) {
      mbuf[(size_t)(btbase + tid) * NSQ + sq] = -INFINITY;
      lbuf[(size_t)(btbase + tid) * NSQ + sq] = 0.f;
    }
    return;
  }

  const float sumv = allreduce_sum(v[tid], red, tid);

  const int s = s0 + tid;
  const bool valid = s < len;
  const float* teRow = te + ((size_t)b * NS + s) * NH;
  const float* tqB = tq + (size_t)btbase * NH;

  float accA[TT], accB[TT];
  #pragma unroll
  for (int t = 0; t < TT; ++t) { accA[t] = 0.f; accB[t] = 0.f; }

  for (int hc = 0; hc < NH; hc += 8) {
    float4 te0 = *(const float4*)(teRow + hc);
    float4 te1 = *(const float4*)(teRow + hc + 4);
    float4 v0  = *(const float4*)(v + hc);
    float4 v1  = *(const float4*)(v + hc + 4);
    #pragma unroll
    for (int t = 0; t < TT; ++t) {
      const float* tqr = tqB + (size_t)t * NH + hc;
      float4 q0 = *(const float4*)(tqr);
      float4 q1 = *(const float4*)(tqr + 4);
      PAIR(q0.x, te0.x, v0.x, q0.y, te0.y, v0.y, accA[t]);
      PAIR(q0.z, te0.z, v0.z, q0.w, te0.w, v0.w, accB[t]);
      PAIR(q1.x, te1.x, v1.x, q1.y, te1.y, v1.y, accA[t]);
      PAIR(q1.z, te1.z, v1.z, q1.w, te1.w, v1.w, accB[t]);
    }
  }

  // per-t softmax partials over this slab's 256 s
  #pragma unroll
  for (int t = 0; t < TT; ++t) {
    float score = valid ? fmaf(-2.f, accA[t] + accB[t], sumv) : -INFINITY;
    float m = allreduce_max(score, red, tid);
    float p = __builtin_amdgcn_exp2f((score - m) * LOG2E);  // -inf -> 0
    float l = allreduce_sum(p, red, tid);
    p_lds[t][tid] = p;
    if (tid == 0) { ml[0][t] = m; ml[1][t] = l; }
  }
  __syncthreads();

  // partial PV: thread owns column h = tid
  float outv[TT];
  #pragma unroll
  for (int t = 0; t < TT; ++t) outv[t] = 0.f;
  const float* encB = enc + ((size_t)b * NS + s0) * NH + tid;
  for (int sl = 0; sl < SBK; sl += 8) {
    float4 pv[TT][2];
    #pragma unroll
    for (int t = 0; t < TT; ++t) {
      pv[t][0] = *(const float4*)&p_lds[t][sl];
      pv[t][1] = *(const float4*)&p_lds[t][sl + 4];
    }
    float e[8];
    #pragma unroll
    for (int j = 0; j < 8; ++j) e[j] = encB[(size_t)(sl + j) * NH];
    #pragma unroll
    for (int t = 0; t < TT; ++t) {
      outv[t] = fmaf(pv[t][0].x, e[0], outv[t]);
      outv[t] = fmaf(pv[t][0].y, e[1], outv[t]);
      outv[t] = fmaf(pv[t][0].z, e[2], outv[t]);
      outv[t] = fmaf(pv[t][0].w, e[3], outv[t]);
      outv[t] = fmaf(pv[t][1].x, e[4], outv[t]);
      outv[t] = fmaf(pv[t][1].y, e[5], outv[t]);
      outv[t] = fmaf(pv[t][1].z, e[6], outv[t]);
      outv[t] = fmaf(pv[t][1].w, e[7], outv[t]);
    }
  }
  #pragma unroll
  for (int t = 0; t < TT; ++t)
    po[((size_t)(btbase + t) * NSQ + sq) * NH + tid] = outv[t];
  if (tid < TT) {
    mbuf[(size_t)(btbase + tid) * NSQ + sq] = ml[0][tid];
    lbuf[(size_t)(btbase + tid) * NSQ + sq] = ml[1][tid];
  }
}

// ---------- combine the NSQ slab-partials per (b,t) ----------
__global__ __launch_bounds__(256) void combine_kernel(const float* __restrict__ po,
                                                      const float* __restrict__ mbuf,
                                                      const float* __restrict__ lbuf,
                                                      float* __restrict__ out) {
  const int bt = blockIdx.x;
  const int h = threadIdx.x;
  float m[NSQ], l[NSQ];
  float M = -INFINITY;
  #pragma unroll
  for (int i = 0; i < NSQ; ++i) {
    m[i] = mbuf[(size_t)bt * NSQ + i];
    l[i] = lbuf[(size_t)bt * NSQ + i];
    M = fmaxf(M, m[i]);
  }
  float L = 0.f, o = 0.f;
  #pragma unroll
  for (int i = 0; i < NSQ; ++i) {
    float w = __builtin_amdgcn_exp2f((m[i] - M) * LOG2E);  // m=-inf -> w=0
    L = fmaf(w, l[i], L);
    o = fmaf(w, po[((size_t)bt * NSQ + i) * NH + h], o);
  }
  out[(size_t)bt * NH + h] = o / L;
}

extern "C" void kernel_launch(void* const* d_in, const int* in_sizes, int n_in,
                              void* d_out, int out_size, void* d_ws, size_t ws_size,
                              hipStream_t stream) {
  const float* query = (const float*)d_in[0];
  const float* enc   = (const float*)d_in[1];
  const int*   slen  = (const int*)d_in[2];
  const float* W_h   = (const float*)d_in[3];
  const float* W_s   = (const float*)d_in[4];
  const float* v     = (const float*)d_in[5];
  float* out = (float*)d_out;

  float* ws = (float*)d_ws;
  float* tq = ws;                                  // B*T*H
  float* te = tq + (size_t)NB * NT * NH;           // B*S*H
  float* po = te + (size_t)NB * NS * NH;           // B*T*NSQ*H
  float* mb = po + (size_t)NB * NT * NSQ * NH;     // B*T*NSQ
  float* lb = mb + (size_t)NB * NT * NSQ;          // B*T*NSQ

  hipLaunchKernelGGL(proj_kernel, dim3((NB * (NT + NS)) / 64, NH / 64), dim3(256), 0, stream,
                     query, enc, W_h, W_s, tq, te);
  hipLaunchKernelGGL(attn_main_kernel, dim3(NSQ, NT / TT, NB), dim3(256), 0, stream,
                     tq, te, enc, slen, v, po, mb, lb);
  hipLaunchKernelGGL(combine_kernel, dim3(NB * NT), dim3(256), 0, stream, po, mb, lb, out);
}

// Round 3
// 75.539 us; speedup vs baseline: 1.3959x; 1.3519x over previous
//
#include <hip/hip_runtime.h>
#include <math.h>

#define NB 4
#define NT 256
#define NS 1024
#define NH 256
#define TT 4          // t rows per main block
#define SBK 256       // s per main block
#define NSQ (NS / SBK)
#define BS (NB * NS)  // 4096 encoder rows total

static constexpr float CTWO   = 2.8853900817779268f; // 2*log2(e)
static constexpr float LOG2E  = 1.4426950408889634f;
static constexpr float ACLAMP = 62.0f;

// ---------- merged projection ----------
// rows [0, NB*NT): query x W_h -> tq, row-major [r][n]  (read via scalar loads later)
// rows [NB*NT, ..): enc x W_s -> te4, h-major float4-interleaved:
//     te4[(n>>2) * (BS*4) + r*4 + (n&3)]  == viewed as float4[64][BS]: [h4][r]
// value = exp2(clamp(CTWO * sum_k A[r][k]*W[k][n]))
__global__ __launch_bounds__(256) void proj_kernel(const float* __restrict__ Q,
                                                   const float* __restrict__ E,
                                                   const float* __restrict__ W_h,
                                                   const float* __restrict__ W_s,
                                                   float* __restrict__ tq,
                                                   float* __restrict__ te4) {
  __shared__ float As[32][68];   // [k][m], padded
  __shared__ float Bs[32][68];   // [k][n], padded
  const int tid = threadIdx.x;
  int r0 = blockIdx.x * 64;
  const int n0 = blockIdx.y * 64;
  const bool is_q = (r0 < NB * NT);
  const float* A;
  const float* W;
  if (is_q) { A = Q; W = W_h; }
  else      { A = E; W = W_s; r0 -= NB * NT; }
  const int tx = tid & 15;
  const int ty = tid >> 4;
  float acc[4][4] = {};
  for (int k0 = 0; k0 < NH; k0 += 32) {
    {
      const int r = tid >> 2;
      const int kq = (tid & 3) * 8;
      const float* src = A + (size_t)(r0 + r) * NH + k0 + kq;
      float4 v0 = *(const float4*)(src);
      float4 v1 = *(const float4*)(src + 4);
      As[kq + 0][r] = v0.x; As[kq + 1][r] = v0.y; As[kq + 2][r] = v0.z; As[kq + 3][r] = v0.w;
      As[kq + 4][r] = v1.x; As[kq + 5][r] = v1.y; As[kq + 6][r] = v1.z; As[kq + 7][r] = v1.w;
    }
    {
      const int k = tid >> 3;
      const int nq = (tid & 7) * 8;
      const float* src = W + (size_t)(k0 + k) * NH + n0 + nq;
      *(float4*)&Bs[k][nq]     = *(const float4*)(src);
      *(float4*)&Bs[k][nq + 4] = *(const float4*)(src + 4);
    }
    __syncthreads();
    #pragma unroll
    for (int k = 0; k < 32; ++k) {
      float4 a = *(const float4*)&As[k][ty * 4];
      float4 b = *(const float4*)&Bs[k][tx * 4];
      const float av[4] = {a.x, a.y, a.z, a.w};
      const float bv[4] = {b.x, b.y, b.z, b.w};
      #pragma unroll
      for (int i = 0; i < 4; ++i)
        #pragma unroll
        for (int j = 0; j < 4; ++j)
          acc[i][j] = fmaf(av[i], bv[j], acc[i][j]);
    }
    __syncthreads();
  }
  #pragma unroll
  for (int i = 0; i < 4; ++i) {
    float vals[4];
    #pragma unroll
    for (int j = 0; j < 4; ++j) {
      float x = acc[i][j] * CTWO;
      x = fminf(fmaxf(x, -ACLAMP), ACLAMP);
      vals[j] = __builtin_amdgcn_exp2f(x);
    }
    const int r = r0 + ty * 4 + i;
    if (is_q) {
      #pragma unroll
      for (int j = 0; j < 4; ++j)
        tq[(size_t)r * NH + n0 + tx * 4 + j] = vals[j];
    } else {
      // h4 group = (n0 + tx*4)/4, 4 consecutive floats per row
      const int h4 = (n0 >> 2) + tx;
      float4 w = {vals[0], vals[1], vals[2], vals[3]};
      *(float4*)&te4[((size_t)h4 * BS + r) * 4] = w;
    }
  }
}

// ---------- block-wide allreduce helpers (256 threads = 4 waves) ----------
__device__ __forceinline__ float allreduce_max(float x, float* red, int tid) {
  #pragma unroll
  for (int o = 32; o > 0; o >>= 1) x = fmaxf(x, __shfl_xor(x, o, 64));
  __syncthreads();
  if ((tid & 63) == 0) red[tid >> 6] = x;
  __syncthreads();
  return fmaxf(fmaxf(red[0], red[1]), fmaxf(red[2], red[3]));
}

__device__ __forceinline__ float allreduce_sum(float x, float* red, int tid) {
  #pragma unroll
  for (int o = 32; o > 0; o >>= 1) x += __shfl_xor(x, o, 64);
  __syncthreads();
  if ((tid & 63) == 0) red[tid >> 6] = x;
  __syncthreads();
  return (red[0] + red[1]) + (red[2] + red[3]);
}

// paired-rcp accumulate: v1/ta + v2/tb = (v1*tb + v2*ta) / (ta*tb)
#define PAIR(qa, ea, va, qb, eb, vb, ACC)                                  \
  {                                                                        \
    float ta = fmaf((qa), (ea), 1.0f);                                     \
    float tb = fmaf((qb), (eb), 1.0f);                                     \
    float num = fmaf((va), tb, (vb) * ta);                                 \
    float den = ta * tb;                                                   \
    ACC = fmaf(num, __builtin_amdgcn_rcpf(den), ACC);                      \
  }

// ---------- main: scores + partial softmax + partial PV per (b, t-tile, s-slab) ----------
__global__ __launch_bounds__(256) void attn_main_kernel(
    const float4* __restrict__ tqq,   // [row][64] float4 view of tq
    const float4* __restrict__ te4q,  // [h4][BS] float4 view of te4
    const float* __restrict__ enc, const int* __restrict__ src_len,
    const float4* __restrict__ vq,    // [64] float4 view of v
    float* __restrict__ po, float* __restrict__ mbuf, float* __restrict__ lbuf) {
  __shared__ float p_lds[TT][SBK];
  __shared__ float red[4];
  __shared__ float ml[2][TT];
  const int tid = threadIdx.x;
  const int sq = blockIdx.x;
  const int tt = blockIdx.y;
  const int b  = blockIdx.z;
  const int s0 = sq * SBK;
  const int len = src_len[b];
  const int btbase = b * NT + tt * TT;

  if (s0 >= len) {  // whole slab masked out
    #pragma unroll
    for (int t = 0; t < TT; ++t)
      po[((size_t)(btbase + t) * NSQ + sq) * NH + tid] = 0.f;
    if (tid < TT) {
      mbuf[(size_t)(btbase + tid) * NSQ + sq] = -INFINITY;
      lbuf[(size_t)(btbase + tid) * NSQ + sq] = 0.f;
    }
    return;
  }

  // sum of v (uniform scalar math, tiny)
  float sv = 0.f;
  {
    const float* vf = (const float*)vq;
    sv = vf[tid];
  }
  const float sumv = allreduce_sum(sv, red, tid);

  const int s = s0 + tid;
  const bool valid = s < len;
  const int gs = b * NS + s;

  float acc0[TT], acc1[TT];
  #pragma unroll
  for (int t = 0; t < TT; ++t) { acc0[t] = 0.f; acc1[t] = 0.f; }

  #pragma unroll 8
  for (int h4 = 0; h4 < NH / 4; ++h4) {
    const float4 e = te4q[(size_t)h4 * BS + gs];  // coalesced dwordx4
    const float4 vv = vq[h4];                     // uniform -> scalar load
    #pragma unroll
    for (int t = 0; t < TT; ++t) {
      const float4 q = tqq[(size_t)(btbase + t) * (NH / 4) + h4];  // uniform
      PAIR(q.x, e.x, vv.x, q.y, e.y, vv.y, acc0[t]);
      PAIR(q.z, e.z, vv.z, q.w, e.w, vv.w, acc1[t]);
    }
  }

  // per-t softmax partials over this slab's 256 s
  #pragma unroll
  for (int t = 0; t < TT; ++t) {
    float score = valid ? fmaf(-2.f, acc0[t] + acc1[t], sumv) : -INFINITY;
    float m = allreduce_max(score, red, tid);
    float p = __builtin_amdgcn_exp2f((score - m) * LOG2E);  // -inf -> 0
    float l = allreduce_sum(p, red, tid);
    p_lds[t][tid] = p;
    if (tid == 0) { ml[0][t] = m; ml[1][t] = l; }
  }
  __syncthreads();

  // partial PV: thread owns column h = tid (coalesced enc reads)
  float outv[TT];
  #pragma unroll
  for (int t = 0; t < TT; ++t) outv[t] = 0.f;
  const float* encB = enc + ((size_t)b * NS + s0) * NH + tid;
  for (int sl = 0; sl < SBK; sl += 8) {
    float4 pv[TT][2];
    #pragma unroll
    for (int t = 0; t < TT; ++t) {
      pv[t][0] = *(const float4*)&p_lds[t][sl];
      pv[t][1] = *(const float4*)&p_lds[t][sl + 4];
    }
    float e[8];
    #pragma unroll
    for (int j = 0; j < 8; ++j) e[j] = encB[(size_t)(sl + j) * NH];
    #pragma unroll
    for (int t = 0; t < TT; ++t) {
      outv[t] = fmaf(pv[t][0].x, e[0], outv[t]);
      outv[t] = fmaf(pv[t][0].y, e[1], outv[t]);
      outv[t] = fmaf(pv[t][0].z, e[2], outv[t]);
      outv[t] = fmaf(pv[t][0].w, e[3], outv[t]);
      outv[t] = fmaf(pv[t][1].x, e[4], outv[t]);
      outv[t] = fmaf(pv[t][1].y, e[5], outv[t]);
      outv[t] = fmaf(pv[t][1].z, e[6], outv[t]);
      outv[t] = fmaf(pv[t][1].w, e[7], outv[t]);
    }
  }
  #pragma unroll
  for (int t = 0; t < TT; ++t)
    po[((size_t)(btbase + t) * NSQ + sq) * NH + tid] = outv[t];
  if (tid < TT) {
    mbuf[(size_t)(btbase + tid) * NSQ + sq] = ml[0][tid];
    lbuf[(size_t)(btbase + tid) * NSQ + sq] = ml[1][tid];
  }
}

// ---------- combine the NSQ slab-partials per (b,t) ----------
__global__ __launch_bounds__(256) void combine_kernel(const float* __restrict__ po,
                                                      const float* __restrict__ mbuf,
                                                      const float* __restrict__ lbuf,
                                                      float* __restrict__ out) {
  const int bt = blockIdx.x;
  const int h = threadIdx.x;
  float m[NSQ], l[NSQ];
  float M = -INFINITY;
  #pragma unroll
  for (int i = 0; i < NSQ; ++i) {
    m[i] = mbuf[(size_t)bt * NSQ + i];
    l[i] = lbuf[(size_t)bt * NSQ + i];
    M = fmaxf(M, m[i]);
  }
  float L = 0.f, o = 0.f;
  #pragma unroll
  for (int i = 0; i < NSQ; ++i) {
    float w = __builtin_amdgcn_exp2f((m[i] - M) * LOG2E);  // m=-inf -> w=0
    L = fmaf(w, l[i], L);
    o = fmaf(w, po[((size_t)bt * NSQ + i) * NH + h], o);
  }
  out[(size_t)bt * NH + h] = o / L;
}

extern "C" void kernel_launch(void* const* d_in, const int* in_sizes, int n_in,
                              void* d_out, int out_size, void* d_ws, size_t ws_size,
                              hipStream_t stream) {
  const float* query = (const float*)d_in[0];
  const float* enc   = (const float*)d_in[1];
  const int*   slen  = (const int*)d_in[2];
  const float* W_h   = (const float*)d_in[3];
  const float* W_s   = (const float*)d_in[4];
  const float* v     = (const float*)d_in[5];
  float* out = (float*)d_out;

  float* ws = (float*)d_ws;
  float* tq  = ws;                                 // NB*NT*NH
  float* te4 = tq + (size_t)NB * NT * NH;          // NB*NS*NH (h4-interleaved)
  float* po  = te4 + (size_t)NB * NS * NH;         // NB*NT*NSQ*NH
  float* mb  = po + (size_t)NB * NT * NSQ * NH;    // NB*NT*NSQ
  float* lb  = mb + (size_t)NB * NT * NSQ;         // NB*NT*NSQ

  hipLaunchKernelGGL(proj_kernel, dim3((NB * (NT + NS)) / 64, NH / 64), dim3(256), 0, stream,
                     query, enc, W_h, W_s, tq, te4);
  hipLaunchKernelGGL(attn_main_kernel, dim3(NSQ, NT / TT, NB), dim3(256), 0, stream,
                     (const float4*)tq, (const float4*)te4, enc, slen, (const float4*)v,
                     po, mb, lb);
  hipLaunchKernelGGL(combine_kernel, dim3(NB * NT), dim3(256), 0, stream, po, mb, lb, out);
}

// Round 4
// 73.883 us; speedup vs baseline: 1.4272x; 1.0224x over previous
//
#include <hip/hip_runtime.h>
#include <math.h>

#define NB 4
#define NT 256
#define NS 1024
#define NH 256
#define TT 2            // t rows per WAVE
#define SBK 128         // s per WAVE (2 s per lane)
#define NSQ (NS / SBK)  // 8
#define BS (NB * NS)    // 4096 encoder rows

static constexpr float CTWO   = 2.8853900817779268f; // 2*log2(e)
static constexpr float LOG2E  = 1.4426950408889634f;
static constexpr float ACLAMP = 62.0f;

// ---------- merged projection ----------
// rows [0, NB*NT): query x W_h -> tq row-major [r][n]
// rows [NB*NT,..): enc x W_s -> te4 float4-view layout [h4][BS]
// value = exp2(clamp(CTWO * sum_k A[r][k]*W[k][n]))
__global__ __launch_bounds__(256) void proj_kernel(const float* __restrict__ Q,
                                                   const float* __restrict__ E,
                                                   const float* __restrict__ W_h,
                                                   const float* __restrict__ W_s,
                                                   float* __restrict__ tq,
                                                   float* __restrict__ te4) {
  __shared__ float As[32][68];
  __shared__ float Bs[32][68];
  const int tid = threadIdx.x;
  int r0 = blockIdx.x * 64;
  const int n0 = blockIdx.y * 64;
  const bool is_q = (r0 < NB * NT);
  const float* A;
  const float* W;
  if (is_q) { A = Q; W = W_h; }
  else      { A = E; W = W_s; r0 -= NB * NT; }
  const int tx = tid & 15;
  const int ty = tid >> 4;
  float acc[4][4] = {};
  for (int k0 = 0; k0 < NH; k0 += 32) {
    {
      const int r = tid >> 2;
      const int kq = (tid & 3) * 8;
      const float* src = A + (size_t)(r0 + r) * NH + k0 + kq;
      float4 v0 = *(const float4*)(src);
      float4 v1 = *(const float4*)(src + 4);
      As[kq + 0][r] = v0.x; As[kq + 1][r] = v0.y; As[kq + 2][r] = v0.z; As[kq + 3][r] = v0.w;
      As[kq + 4][r] = v1.x; As[kq + 5][r] = v1.y; As[kq + 6][r] = v1.z; As[kq + 7][r] = v1.w;
    }
    {
      const int k = tid >> 3;
      const int nq = (tid & 7) * 8;
      const float* src = W + (size_t)(k0 + k) * NH + n0 + nq;
      *(float4*)&Bs[k][nq]     = *(const float4*)(src);
      *(float4*)&Bs[k][nq + 4] = *(const float4*)(src + 4);
    }
    __syncthreads();
    #pragma unroll
    for (int k = 0; k < 32; ++k) {
      float4 a = *(const float4*)&As[k][ty * 4];
      float4 b = *(const float4*)&Bs[k][tx * 4];
      const float av[4] = {a.x, a.y, a.z, a.w};
      const float bv[4] = {b.x, b.y, b.z, b.w};
      #pragma unroll
      for (int i = 0; i < 4; ++i)
        #pragma unroll
        for (int j = 0; j < 4; ++j)
          acc[i][j] = fmaf(av[i], bv[j], acc[i][j]);
    }
    __syncthreads();
  }
  #pragma unroll
  for (int i = 0; i < 4; ++i) {
    float vals[4];
    #pragma unroll
    for (int j = 0; j < 4; ++j) {
      float x = acc[i][j] * CTWO;
      x = fminf(fmaxf(x, -ACLAMP), ACLAMP);
      vals[j] = __builtin_amdgcn_exp2f(x);
    }
    const int r = r0 + ty * 4 + i;
    if (is_q) {
      #pragma unroll
      for (int j = 0; j < 4; ++j)
        tq[(size_t)r * NH + n0 + tx * 4 + j] = vals[j];
    } else {
      const int h4 = (n0 >> 2) + tx;
      float4 w = {vals[0], vals[1], vals[2], vals[3]};
      *(float4*)&te4[((size_t)h4 * BS + r) * 4] = w;
    }
  }
}

// paired-rcp accumulate: v1/ta + v2/tb = (v1*tb + v2*ta) / (ta*tb)
// num always finite (|v|<1, t<2^125); den may overflow->inf->rcp 0 (correct limit).
#define PAIR(qa, ea, va, qb, eb, vb, ACC)                                  \
  {                                                                        \
    float ta = fmaf((qa), (ea), 1.0f);                                     \
    float tb = fmaf((qb), (eb), 1.0f);                                     \
    float num = fmaf((va), tb, (vb) * ta);                                 \
    float den = ta * tb;                                                   \
    ACC = fmaf(num, __builtin_amdgcn_rcpf(den), ACC);                      \
  }

// ---------- main: one WAVE owns (b, TT t-rows, 128-s slab). No barriers. ----------
__global__ __launch_bounds__(256) void attn_main_kernel(
    const float4* __restrict__ tqq,   // [row][64] float4 view of tq
    const float4* __restrict__ te4q,  // [h4][BS] float4 view
    const float4* __restrict__ enc4,  // [row][64] float4 view of enc
    const int* __restrict__ src_len,
    const float4* __restrict__ vq,    // [64]
    float4* __restrict__ po4, float* __restrict__ mbuf, float* __restrict__ lbuf) {
  __shared__ float p_lds[4][TT][SBK];
  const int tid = threadIdx.x;
  const int wid = tid >> 6;
  const int lane = tid & 63;
  const int bx = blockIdx.x;
  // wave -> (b, tt, sq): each block mixes 4 spread sq values (valid+masked mix)
  const int sq = wid * 2 + (bx & 1);
  const int b  = (bx >> 1) & 3;
  const int tt = bx >> 3;
  const int btbase = b * NT + tt * TT;
  const int s0 = sq * SBK;
  const int len = src_len[b];

  if (s0 >= len) {  // masked slab: only m/l needed (combine skips po when m=-inf)
    if (lane < TT) {
      mbuf[(size_t)(btbase + lane) * NSQ + sq] = -INFINITY;
      lbuf[(size_t)(btbase + lane) * NSQ + sq] = 0.f;
    }
    return;
  }

  // sum(v): lane holds 4 components, wave shfl-reduce
  float sumv;
  {
    float4 v4 = vq[lane];
    float sv = (v4.x + v4.y) + (v4.z + v4.w);
    #pragma unroll
    for (int o = 32; o > 0; o >>= 1) sv += __shfl_xor(sv, o, 64);
    sumv = sv;
  }

  const int gs0 = b * NS + s0;
  const int sa = s0 + lane;
  const int sb = s0 + 64 + lane;
  const bool va_ok = sa < len;
  const bool vb_ok = sb < len;

  float accA0[TT], accA1[TT], accB0[TT], accB1[TT];
  #pragma unroll
  for (int t = 0; t < TT; ++t) { accA0[t] = accA1[t] = accB0[t] = accB1[t] = 0.f; }

  #pragma unroll 4
  for (int h4 = 0; h4 < NH / 4; ++h4) {
    const float4 ea = te4q[(size_t)h4 * BS + gs0 + lane];        // coalesced 1KB/wave
    const float4 eb = te4q[(size_t)h4 * BS + gs0 + 64 + lane];
    const float4 vv = vq[h4];                                    // scalar
    #pragma unroll
    for (int t = 0; t < TT; ++t) {
      const float4 q = tqq[(size_t)(btbase + t) * (NH / 4) + h4]; // scalar
      PAIR(q.x, ea.x, vv.x, q.y, ea.y, vv.y, accA0[t]);
      PAIR(q.z, ea.z, vv.z, q.w, ea.w, vv.w, accA1[t]);
      PAIR(q.x, eb.x, vv.x, q.y, eb.y, vv.y, accB0[t]);
      PAIR(q.z, eb.z, vv.z, q.w, eb.w, vv.w, accB1[t]);
    }
  }

  // wave-local softmax partials (no barriers; lane0 of slab always valid -> m finite)
  #pragma unroll
  for (int t = 0; t < TT; ++t) {
    float xa = va_ok ? fmaf(-2.f, accA0[t] + accA1[t], sumv) : -INFINITY;
    float xb = vb_ok ? fmaf(-2.f, accB0[t] + accB1[t], sumv) : -INFINITY;
    float m = fmaxf(xa, xb);
    #pragma unroll
    for (int o = 32; o > 0; o >>= 1) m = fmaxf(m, __shfl_xor(m, o, 64));
    float pa = __builtin_amdgcn_exp2f((xa - m) * LOG2E);
    float pb = __builtin_amdgcn_exp2f((xb - m) * LOG2E);
    float l = pa + pb;
    #pragma unroll
    for (int o = 32; o > 0; o >>= 1) l += __shfl_xor(l, o, 64);
    p_lds[wid][t][lane] = pa;
    p_lds[wid][t][64 + lane] = pb;
    if (lane == 0) {
      mbuf[(size_t)(btbase + t) * NSQ + sq] = m;
      lbuf[(size_t)(btbase + t) * NSQ + sq] = l;
    }
  }

  // PV: lane owns h-columns [lane*4, lane*4+4): dwordx4 enc loads, LDS b128 broadcast
  float4 o[TT];
  #pragma unroll
  for (int t = 0; t < TT; ++t) o[t] = make_float4(0.f, 0.f, 0.f, 0.f);
  #pragma unroll 2
  for (int s = 0; s < SBK; s += 4) {
    float4 e0 = enc4[(size_t)(gs0 + s + 0) * (NH / 4) + lane];
    float4 e1 = enc4[(size_t)(gs0 + s + 1) * (NH / 4) + lane];
    float4 e2 = enc4[(size_t)(gs0 + s + 2) * (NH / 4) + lane];
    float4 e3 = enc4[(size_t)(gs0 + s + 3) * (NH / 4) + lane];
    #pragma unroll
    for (int t = 0; t < TT; ++t) {
      float4 p = *(const float4*)&p_lds[wid][t][s];  // same-addr broadcast
      o[t].x = fmaf(p.x, e0.x, o[t].x); o[t].y = fmaf(p.x, e0.y, o[t].y);
      o[t].z = fmaf(p.x, e0.z, o[t].z); o[t].w = fmaf(p.x, e0.w, o[t].w);
      o[t].x = fmaf(p.y, e1.x, o[t].x); o[t].y = fmaf(p.y, e1.y, o[t].y);
      o[t].z = fmaf(p.y, e1.z, o[t].z); o[t].w = fmaf(p.y, e1.w, o[t].w);
      o[t].x = fmaf(p.z, e2.x, o[t].x); o[t].y = fmaf(p.z, e2.y, o[t].y);
      o[t].z = fmaf(p.z, e2.z, o[t].z); o[t].w = fmaf(p.z, e2.w, o[t].w);
      o[t].x = fmaf(p.w, e3.x, o[t].x); o[t].y = fmaf(p.w, e3.y, o[t].y);
      o[t].z = fmaf(p.w, e3.z, o[t].z); o[t].w = fmaf(p.w, e3.w, o[t].w);
    }
  }
  #pragma unroll
  for (int t = 0; t < TT; ++t)
    po4[((size_t)(btbase + t) * NSQ + sq) * (NH / 4) + lane] = o[t];
}

// ---------- combine the NSQ slab-partials per (b,t); skip masked (m=-inf) ----------
__global__ __launch_bounds__(256) void combine_kernel(const float* __restrict__ po,
                                                      const float* __restrict__ mbuf,
                                                      const float* __restrict__ lbuf,
                                                      float* __restrict__ out) {
  const int bt = blockIdx.x;
  const int h = threadIdx.x;
  float m[NSQ], l[NSQ];
  float M = -INFINITY;
  #pragma unroll
  for (int i = 0; i < NSQ; ++i) {
    m[i] = mbuf[(size_t)bt * NSQ + i];
    l[i] = lbuf[(size_t)bt * NSQ + i];
    M = fmaxf(M, m[i]);
  }
  float L = 0.f, o = 0.f;
  #pragma unroll
  for (int i = 0; i < NSQ; ++i) {
    if (m[i] > -INFINITY) {  // uniform branch per block
      float w = __builtin_amdgcn_exp2f((m[i] - M) * LOG2E);
      L = fmaf(w, l[i], L);
      o = fmaf(w, po[((size_t)bt * NSQ + i) * NH + h], o);
    }
  }
  out[(size_t)bt * NH + h] = o / L;
}

extern "C" void kernel_launch(void* const* d_in, const int* in_sizes, int n_in,
                              void* d_out, int out_size, void* d_ws, size_t ws_size,
                              hipStream_t stream) {
  const float* query = (const float*)d_in[0];
  const float* enc   = (const float*)d_in[1];
  const int*   slen  = (const int*)d_in[2];
  const float* W_h   = (const float*)d_in[3];
  const float* W_s   = (const float*)d_in[4];
  const float* v     = (const float*)d_in[5];
  float* out = (float*)d_out;

  float* ws = (float*)d_ws;
  float* tq  = ws;                                 // NB*NT*NH          (1 MB)
  float* te4 = tq + (size_t)NB * NT * NH;          // NB*NS*NH          (4 MB)
  float* po  = te4 + (size_t)NB * NS * NH;         // NB*NT*NSQ*NH      (8 MB)
  float* mb  = po + (size_t)NB * NT * NSQ * NH;    // NB*NT*NSQ
  float* lb  = mb + (size_t)NB * NT * NSQ;         // NB*NT*NSQ

  hipLaunchKernelGGL(proj_kernel, dim3((NB * (NT + NS)) / 64, NH / 64), dim3(256), 0, stream,
                     query, enc, W_h, W_s, tq, te4);
  // waves = NB * (NT/TT) * NSQ = 4096; blocks of 4 waves
  hipLaunchKernelGGL(attn_main_kernel, dim3(NB * (NT / TT) * NSQ / 4), dim3(256), 0, stream,
                     (const float4*)tq, (const float4*)te4, (const float4*)enc, slen,
                     (const float4*)v, (float4*)po, mb, lb);
  hipLaunchKernelGGL(combine_kernel, dim3(NB * NT), dim3(256), 0, stream, po, mb, lb, out);
}